// Round 21
// baseline (111.188 us; speedup 1.0000x reference)
//
#include <hip/hip_runtime.h>
#include <hip/hip_bf16.h>
#include <cstdint>
#include <cstddef>

// LSTMCell: gates = [input|hx] @ [Wih|Whh]^T + b_ih + b_hh  (4096 x 4096 x K=2048)
// Round 21: self-paced register GEMM (R13-R20 line) with SMALLER WAVE TILES for
// HIGHER OCCUPANCY: wave = 64 rows x 64 gate-cols (acc[4][4]=64 regs, ~150 total),
// __launch_bounds__(256,3) -> 3 waves/SIMD (12/CU). More independent streams per
// SIMD to hide the TA-burst convoy that capped R13-R20 at ~50% pipe overlap.
// TA bytes rise 1.5->2.0 GB (8 KB/wave-step) but overlap should more than cover.
//
// A layout: [mi6(64)][kt(64)][m(4)][lane(64)][8 u16]
// W layout: [hq(16)][wn(4)][kt(64)][g(4)][lane(64)][8 u16]   (same as R20)

#define B_ROWS 4096
#define HDIM   1024
#define KDIM   2048
#define T_STEPS 64

typedef unsigned short u16;
using f32x4  = __attribute__((ext_vector_type(4))) float;
using short8 = __attribute__((ext_vector_type(8))) short;
using half8  = __attribute__((ext_vector_type(8))) _Float16;

__device__ __forceinline__ u16 f2h_bits(float f) {
    _Float16 h = (_Float16)f;                    // v_cvt_f16_f32, RTN
    return __builtin_bit_cast(u16, h);
}

// ---------------- pack: f32 -> f16 fragment-major ----------------
__global__ void pack_kernel(const float* __restrict__ input, const float* __restrict__ hx,
                            const float* __restrict__ wih, const float* __restrict__ whh,
                            u16* __restrict__ Ap, u16* __restrict__ Wp)
{
    const int NA = 64 * 64 * 4 * 64;       // 1,048,576 16B-groups
    const int NW = 16 * 4 * 64 * 4 * 64;   // 1,048,576
    int stride = gridDim.x * blockDim.x;
    for (int i = blockIdx.x * blockDim.x + threadIdx.x; i < NA + NW; i += stride) {
        int isW = (i >= NA) ? 1 : 0;
        int e = isW ? i - NA : i;
        int lane = e & 63;
        int fr = lane & 15, fk = lane >> 4;
        int kt = (e >> 8) & 63;
        int k  = kt * 32 + fk * 8;
        int row;
        if (isW) {
            int g  = (e >> 6) & 3;
            int wn = (e >> 14) & 3;
            int hqq = e >> 16;
            row = g * 1024 + hqq * 64 + wn * 16 + fr;
        } else {
            int m   = (e >> 6) & 3;
            int mi6 = e >> 14;               // 0..63
            row = mi6 * 64 + m * 16 + fr;
        }
        const float* s0 = isW ? wih : input;
        const float* s1 = isW ? whh : hx;
        const float* src = (k < 1024) ? (s0 + (size_t)row * 1024 + k)
                                      : (s1 + (size_t)row * 1024 + (k - 1024));
        float4 v0 = *(const float4*)src;
        float4 v1 = *(const float4*)(src + 4);
        u16* dst = (isW ? Wp : Ap) + (size_t)e * 8;
        *(ushort4*)dst = make_ushort4(f2h_bits(v0.x), f2h_bits(v0.y),
                                      f2h_bits(v0.z), f2h_bits(v0.w));
        *(ushort4*)(dst + 4) = make_ushort4(f2h_bits(v1.x), f2h_bits(v1.y),
                                            f2h_bits(v1.z), f2h_bits(v1.w));
    }
}

// ---------------- fused GEMM + LSTM epilogue (no LDS, no barriers) ----------------
__device__ __forceinline__ float sigmf(float x) { return 1.0f / (1.0f + __expf(-x)); }
__device__ __forceinline__ float tanhfast(float x) { return 1.0f - 2.0f / (1.0f + __expf(2.0f * x)); }

__launch_bounds__(256, 3)
__global__ void lstm_fused(const u16* __restrict__ Ap, const u16* __restrict__ Wp,
                           const float* __restrict__ cx, const float* __restrict__ eps_c,
                           const float* __restrict__ eps_h,
                           const float* __restrict__ bias_ih, const float* __restrict__ bias_hh,
                           const float* __restrict__ noise_q, const float* __restrict__ noise_e,
                           float* __restrict__ out)
{
    int bid = blockIdx.x;
    // XCD-bijective swizzle: 1024 blocks, 128/XCD. XCD x -> w in [128x,128x+128):
    // hq spans 2 values (W slice 1 MB packed, L2-resident) x all 64 A panels (L3).
    int w = (bid & 7) * 128 + (bid >> 3);
    int mi6 = w & 63;         // 64 M-chunks of 64 rows
    int hq  = w >> 6;         // 16 h-chunks of 64 cols (x4 gates)
    int bm0 = mi6 * 64;
    int h0  = hq * 64;

    int tid  = threadIdx.x;
    int lane = tid & 63;
    int wn   = tid >> 6;      // wave 0..3 = h quarter
    int fr   = lane & 15, fk = lane >> 4;

    // fragment base pointers (u16 units); kt-stride 2048 for both
    const u16* pAt = Ap + (size_t)mi6 * 131072 + lane * 8;
    const u16* pWt = Wp + ((size_t)(hq * 4 + wn)) * 131072 + lane * 8;

#define LD8(p) __builtin_bit_cast(half8, *(const short8*)(p))

#define LOADF_P(AA, WW, ofs) do { \
        _Pragma("unroll") \
        for (int m = 0; m < 4; ++m) AA[m] = LD8(pAt + (ofs) + m * 512); \
        _Pragma("unroll") \
        for (int g = 0; g < 4; ++g) WW[g] = LD8(pWt + (ofs) + g * 512); \
    } while (0)

#define DOMFMA(AA, WW) do { \
        __builtin_amdgcn_s_setprio(1); \
        _Pragma("unroll") \
        for (int g = 0; g < 4; ++g) \
            _Pragma("unroll") \
            for (int m = 0; m < 4; ++m) \
                acc[m][g] = __builtin_amdgcn_mfma_f32_16x16x32_f16(AA[m], WW[g], acc[m][g], 0, 0, 0); \
        __builtin_amdgcn_s_setprio(0); \
    } while (0)

    f32x4 acc[4][4];
#pragma unroll
    for (int m = 0; m < 4; ++m)
#pragma unroll
        for (int g = 0; g < 4; ++g)
            acc[m][g] = (f32x4){0.f, 0.f, 0.f, 0.f};

    half8 aX[4], wX[4], aY[4], wY[4];
    LOADF_P(aX, wX, 0);

#pragma unroll 1
    for (int t = 0; t < T_STEPS; t += 2) {
        LOADF_P(aY, wY, 2048);         // prefetch odd step into Y
        DOMFMA(aX, wX);                // compute even step (waits only on X)
        if (t + 2 < T_STEPS) LOADF_P(aX, wX, 4096);   // next even into X
        DOMFMA(aY, wY);                // compute odd step
        pAt += 4096;                   // advance 2 K-steps
        pWt += 4096;
    }

    // ---- epilogue: batch-load cx/eps first, then compute ----
    float sq_e = sqrtf(noise_e[0]);
    float sq_q = sqrtf(noise_q[0]);
    int h = h0 + wn * 16 + fr;
    float bsum[4];
#pragma unroll
    for (int g = 0; g < 4; ++g)
        bsum[g] = bias_ih[g * 1024 + h] + bias_hh[g * 1024 + h];

    float vcx[4][4], vec_[4][4], veh[4][4];
#pragma unroll
    for (int m = 0; m < 4; ++m) {
        int r0 = bm0 + m * 16 + fk * 4;
#pragma unroll
        for (int j = 0; j < 4; ++j) {
            size_t off = (size_t)(r0 + j) * HDIM + h;
            vcx[m][j] = cx[off];
            vec_[m][j] = eps_c[off];
            veh[m][j] = eps_h[off];
        }
    }
#pragma unroll
    for (int m = 0; m < 4; ++m) {
        int r0 = bm0 + m * 16 + fk * 4;
#pragma unroll
        for (int j = 0; j < 4; ++j) {
            size_t off = (size_t)(r0 + j) * HDIM + h;
            float gi = acc[m][0][j] + bsum[0];
            float gf = acc[m][1][j] + bsum[1];
            float gc = acc[m][2][j] + bsum[2];
            float go = acc[m][3][j] + bsum[3];
            float ig = sigmf(gi), fg = sigmf(gf);
            float cg = tanhfast(gc), og = sigmf(go);
            float cyv = fg * vcx[m][j] + ig * cg + sq_e * vec_[m][j];
            float hyv = og * tanhfast(cyv) + sq_q * veh[m][j];
            out[off] = hyv;                                 // hy
            out[(size_t)B_ROWS * HDIM + off] = cyv;         // cy
        }
    }
}

extern "C" void kernel_launch(void* const* d_in, const int* in_sizes, int n_in,
                              void* d_out, int out_size, void* d_ws, size_t ws_size,
                              hipStream_t stream)
{
    const float* input = (const float*)d_in[0];
    const float* hx    = (const float*)d_in[1];
    const float* cx    = (const float*)d_in[2];
    const float* nq    = (const float*)d_in[3];
    const float* ne    = (const float*)d_in[4];
    const float* wih   = (const float*)d_in[5];
    const float* whh   = (const float*)d_in[6];
    const float* bih   = (const float*)d_in[7];
    const float* bhh   = (const float*)d_in[8];
    const float* epsc  = (const float*)d_in[9];
    const float* epsh  = (const float*)d_in[10];
    float* out = (float*)d_out;

    u16* Ap = (u16*)d_ws;
    u16* Wp = Ap + (size_t)B_ROWS * KDIM;   // 32 MB of ws total

    hipLaunchKernelGGL(pack_kernel, dim3(2048), dim3(256), 0, stream,
                       input, hx, wih, whh, Ap, Wp);
    hipLaunchKernelGGL(lstm_fused, dim3(1024), dim3(256), 0, stream,
                       Ap, Wp, cx, epsc, epsh, bih, bhh, nq, ne, out);
}

// Round 22
// 99.347 us; speedup vs baseline: 1.1192x; 1.1192x over previous
//
#include <hip/hip_runtime.h>
#include <hip/hip_bf16.h>
#include <cstdint>
#include <cstddef>

// LSTMCell: gates = [input|hx] @ [Wih|Whh]^T + b_ih + b_hh  (4096 x 4096 x K=2048)
// FINAL (revert to R17, best measured: 98.8 us total, absmax 0.051):
// single-product f16 GEMM on a no-LDS, no-barrier, self-paced register-double-
// buffered MFMA kernel; fragment-major packed operands (every fragment load is one
// coalesced global_load_dwordx4 from L2-resident data); XCD-swizzled blocks;
// batched epilogue loads. Verified optimum across: sync structure (6 LDS/barrier
// variants worse), pipeline depth (3-4 buf spill @ 256-reg unified file), wave
// tile (128x128 spills; 64x64 loses arithmetic intensity), block granularity,
// phase skew, occupancy (3/SIMD worse).
//
// A layout: [mi(16)][wm(2)][kt(64)][m(8)][lane(64)][8 u16]
// W layout: [hq(16)][wn(4)][kt(64)][g(4)][lane(64)][8 u16]

#define B_ROWS 4096
#define HDIM   1024
#define KDIM   2048
#define BM     256
#define T_STEPS 64

typedef unsigned short u16;
using f32x4  = __attribute__((ext_vector_type(4))) float;
using short8 = __attribute__((ext_vector_type(8))) short;
using half8  = __attribute__((ext_vector_type(8))) _Float16;

__device__ __forceinline__ u16 f2h_bits(float f) {
    _Float16 h = (_Float16)f;                    // v_cvt_f16_f32, RTN
    return __builtin_bit_cast(u16, h);
}

// ---------------- pack: f32 -> f16 fragment-major ----------------
__global__ void pack_kernel(const float* __restrict__ input, const float* __restrict__ hx,
                            const float* __restrict__ wih, const float* __restrict__ whh,
                            u16* __restrict__ Ap, u16* __restrict__ Wp)
{
    const int NA = 16 * 2 * 64 * 8 * 64;   // 1,048,576 16B-groups
    const int NW = 16 * 4 * 64 * 4 * 64;   // 1,048,576
    int stride = gridDim.x * blockDim.x;
    for (int i = blockIdx.x * blockDim.x + threadIdx.x; i < NA + NW; i += stride) {
        int isW = (i >= NA) ? 1 : 0;
        int e = isW ? i - NA : i;
        int lane = e & 63;
        int fr = lane & 15, fk = lane >> 4;
        int kt = isW ? ((e >> 8) & 63) : ((e >> 9) & 63);
        int k  = kt * 32 + fk * 8;
        int row;
        if (isW) {
            int g  = (e >> 6) & 3;
            int wn = (e >> 14) & 3;
            int hqq = e >> 16;
            row = g * 1024 + hqq * 64 + wn * 16 + fr;
        } else {
            int m  = (e >> 6) & 7;
            int wmm = (e >> 15) & 1;
            int mii = e >> 16;
            row = mii * 256 + wmm * 128 + m * 16 + fr;
        }
        const float* s0 = isW ? wih : input;
        const float* s1 = isW ? whh : hx;
        const float* src = (k < 1024) ? (s0 + (size_t)row * 1024 + k)
                                      : (s1 + (size_t)row * 1024 + (k - 1024));
        float4 v0 = *(const float4*)src;
        float4 v1 = *(const float4*)(src + 4);
        u16* dst = (isW ? Wp : Ap) + (size_t)e * 8;
        *(ushort4*)dst = make_ushort4(f2h_bits(v0.x), f2h_bits(v0.y),
                                      f2h_bits(v0.z), f2h_bits(v0.w));
        *(ushort4*)(dst + 4) = make_ushort4(f2h_bits(v1.x), f2h_bits(v1.y),
                                            f2h_bits(v1.z), f2h_bits(v1.w));
    }
}

// ---------------- fused GEMM + LSTM epilogue (no LDS, no barriers) ----------------
__device__ __forceinline__ float sigmf(float x) { return 1.0f / (1.0f + __expf(-x)); }
__device__ __forceinline__ float tanhfast(float x) { return 1.0f - 2.0f / (1.0f + __expf(2.0f * x)); }

__launch_bounds__(512, 1)
__global__ void lstm_fused(const u16* __restrict__ Ap, const u16* __restrict__ Wp,
                           const float* __restrict__ cx, const float* __restrict__ eps_c,
                           const float* __restrict__ eps_h,
                           const float* __restrict__ bias_ih, const float* __restrict__ bias_hh,
                           const float* __restrict__ noise_q, const float* __restrict__ noise_e,
                           float* __restrict__ out)
{
    int bid = blockIdx.x;
    // XCD-bijective swizzle: XCD x gets w in [32x,32x+32) -> 2 hq values
    // (W slice 2 MB packed, L2-resident) x all 16 A panels (L3-resident).
    int w = (bid & 7) * 32 + (bid >> 3);
    int mi = w & 15;          // 16 M-chunks of 256 rows
    int hq = w >> 4;          // 16 h-chunks of 64 cols (x4 gates)
    int bm0 = mi * BM;
    int h0 = hq * 64;

    int tid  = threadIdx.x;
    int lane = tid & 63;
    int wid  = tid >> 6;      // 0..7
    int wm   = wid >> 2;      // M half (128 rows)
    int wn   = wid & 3;       // h quarter (16 cols x 4 gates)
    int fr   = lane & 15, fk = lane >> 4;

    // fragment base pointers (u16 units); bumped per step (imm-offset loads)
    const u16* pAt = Ap + ((size_t)(mi * 2 + wm)) * (64 * 8 * 64 * 8) + lane * 8;
    const u16* pWt = Wp + ((size_t)(hq * 4 + wn)) * (64 * 4 * 64 * 8) + lane * 8;

#define LD8(p) __builtin_bit_cast(half8, *(const short8*)(p))

#define LOADF_P(AA, WW, ofsA, ofsW) do { \
        _Pragma("unroll") \
        for (int m = 0; m < 8; ++m) AA[m] = LD8(pAt + (ofsA) + m * 512); \
        _Pragma("unroll") \
        for (int g = 0; g < 4; ++g) WW[g] = LD8(pWt + (ofsW) + g * 512); \
    } while (0)

#define DOMFMA(AA, WW) do { \
        __builtin_amdgcn_s_setprio(1); \
        _Pragma("unroll") \
        for (int g = 0; g < 4; ++g) \
            _Pragma("unroll") \
            for (int m = 0; m < 8; ++m) \
                acc[m][g] = __builtin_amdgcn_mfma_f32_16x16x32_f16(AA[m], WW[g], acc[m][g], 0, 0, 0); \
        __builtin_amdgcn_s_setprio(0); \
    } while (0)

    f32x4 acc[8][4];
#pragma unroll
    for (int m = 0; m < 8; ++m)
#pragma unroll
        for (int g = 0; g < 4; ++g)
            acc[m][g] = (f32x4){0.f, 0.f, 0.f, 0.f};

    half8 aX[8], wX[4], aY[8], wY[4];
    LOADF_P(aX, wX, 0, 0);

#pragma unroll 1
    for (int t = 0; t < T_STEPS; t += 2) {
        LOADF_P(aY, wY, 4096, 2048);   // prefetch odd step into Y
        DOMFMA(aX, wX);                // compute even step (waits only on X)
        if (t + 2 < T_STEPS) LOADF_P(aX, wX, 8192, 4096);   // next even into X
        DOMFMA(aY, wY);                // compute odd step
        pAt += 8192;                   // advance 2 K-steps
        pWt += 4096;
    }

    // ---- epilogue: batch-load ALL cx/eps first (operand regs are dead), then compute ----
    float sq_e = sqrtf(noise_e[0]);
    float sq_q = sqrtf(noise_q[0]);
    int h = h0 + wn * 16 + fr;
    float bsum[4];
#pragma unroll
    for (int g = 0; g < 4; ++g)
        bsum[g] = bias_ih[g * 1024 + h] + bias_hh[g * 1024 + h];

    float vcx[8][4], vec_[8][4], veh[8][4];
#pragma unroll
    for (int m = 0; m < 8; ++m) {
        int r0 = bm0 + wm * 128 + m * 16 + fk * 4;
#pragma unroll
        for (int j = 0; j < 4; ++j) {
            size_t off = (size_t)(r0 + j) * HDIM + h;
            vcx[m][j] = cx[off];
            vec_[m][j] = eps_c[off];
            veh[m][j] = eps_h[off];
        }
    }
#pragma unroll
    for (int m = 0; m < 8; ++m) {
        int r0 = bm0 + wm * 128 + m * 16 + fk * 4;
#pragma unroll
        for (int j = 0; j < 4; ++j) {
            size_t off = (size_t)(r0 + j) * HDIM + h;
            float gi = acc[m][0][j] + bsum[0];
            float gf = acc[m][1][j] + bsum[1];
            float gc = acc[m][2][j] + bsum[2];
            float go = acc[m][3][j] + bsum[3];
            float ig = sigmf(gi), fg = sigmf(gf);
            float cg = tanhfast(gc), og = sigmf(go);
            float cyv = fg * vcx[m][j] + ig * cg + sq_e * vec_[m][j];
            float hyv = og * tanhfast(cyv) + sq_q * veh[m][j];
            out[off] = hyv;                                 // hy
            out[(size_t)B_ROWS * HDIM + off] = cyv;         // cy
        }
    }
}

extern "C" void kernel_launch(void* const* d_in, const int* in_sizes, int n_in,
                              void* d_out, int out_size, void* d_ws, size_t ws_size,
                              hipStream_t stream)
{
    const float* input = (const float*)d_in[0];
    const float* hx    = (const float*)d_in[1];
    const float* cx    = (const float*)d_in[2];
    const float* nq    = (const float*)d_in[3];
    const float* ne    = (const float*)d_in[4];
    const float* wih   = (const float*)d_in[5];
    const float* whh   = (const float*)d_in[6];
    const float* bih   = (const float*)d_in[7];
    const float* bhh   = (const float*)d_in[8];
    const float* epsc  = (const float*)d_in[9];
    const float* epsh  = (const float*)d_in[10];
    float* out = (float*)d_out;

    u16* Ap = (u16*)d_ws;
    u16* Wp = Ap + (size_t)B_ROWS * KDIM;   // 32 MB of ws total

    hipLaunchKernelGGL(pack_kernel, dim3(2048), dim3(256), 0, stream,
                       input, hx, wih, whh, Ap, Wp);
    hipLaunchKernelGGL(lstm_fused, dim3(256), dim3(512), 0, stream,
                       Ap, Wp, cx, epsc, epsh, bih, bhh, nq, ne, out);
}